// Round 1
// 35128.860 us; speedup vs baseline: 1.0925x; 1.0925x over previous
//
#include <hip/hip_runtime.h>
#include <hip/hip_cooperative_groups.h>

namespace cg = cooperative_groups;

// Problem constants: B=64, T=512, I=H=1024, L=2  (all fp32)
// d_out = y [64,512,1024] ++ h_last [2,64,1024]
// d_ws  = xw [64,512,1024] ++ hq [2][256][64] float4 ++ flags [4*64] int

#define FLAG_LD(p)    __hip_atomic_load((p), __ATOMIC_RELAXED, __HIP_MEMORY_SCOPE_AGENT)
#define FLAG_ST(p, v) __hip_atomic_store((p), (v), __ATOMIC_RELAXED, __HIP_MEMORY_SCOPE_AGENT)

// ---------------------------------------------------------------------------
// proj: C[M,1024] = A[M,1024] @ W[1024,1024]^T + (b1 + b2)
// 128x128 tile, 256 threads, 8x8 micro-tile, BK=16, global prefetch.
// (unchanged — ~0.8 ms each, ~4% of total)
// ---------------------------------------------------------------------------
__global__ __launch_bounds__(256) void proj_kernel(
    const float* __restrict__ A, const float* __restrict__ W,
    const float* __restrict__ b1, const float* __restrict__ b2,
    float* __restrict__ C)
{
    constexpr int Kd = 1024;
    constexpr int Nd = 1024;
    const int n0 = blockIdx.x * 128;
    const int m0 = blockIdx.y * 128;
    __shared__ float As[16 * 128];
    __shared__ float Bs[16 * 128];
    const int tid = threadIdx.x;
    const int tx = tid & 15;
    const int ty = tid >> 4;
    const int lrow = tid >> 2;
    const int lj = (tid & 3) << 2;

    float acc[8][8];
#pragma unroll
    for (int u = 0; u < 8; ++u)
#pragma unroll
        for (int v = 0; v < 8; ++v) acc[u][v] = 0.f;

    const float* Ab0 = A + (long long)(m0 + lrow) * Kd + lj;
    const float* Ab1 = Ab0 + 64ll * Kd;
    const float* Bb0 = W + (long long)(n0 + lrow) * Kd + lj;
    const float* Bb1 = Bb0 + 64ll * Kd;

    float4 pa0 = *(const float4*)(Ab0);
    float4 pa1 = *(const float4*)(Ab1);
    float4 pb0 = *(const float4*)(Bb0);
    float4 pb1 = *(const float4*)(Bb1);

    for (int kk = 0; kk < Kd; kk += 16) {
        __syncthreads();
        As[(lj + 0) * 128 + lrow] = pa0.x;
        As[(lj + 1) * 128 + lrow] = pa0.y;
        As[(lj + 2) * 128 + lrow] = pa0.z;
        As[(lj + 3) * 128 + lrow] = pa0.w;
        As[(lj + 0) * 128 + 64 + lrow] = pa1.x;
        As[(lj + 1) * 128 + 64 + lrow] = pa1.y;
        As[(lj + 2) * 128 + 64 + lrow] = pa1.z;
        As[(lj + 3) * 128 + 64 + lrow] = pa1.w;
        Bs[(lj + 0) * 128 + lrow] = pb0.x;
        Bs[(lj + 1) * 128 + lrow] = pb0.y;
        Bs[(lj + 2) * 128 + lrow] = pb0.z;
        Bs[(lj + 3) * 128 + lrow] = pb0.w;
        Bs[(lj + 0) * 128 + 64 + lrow] = pb1.x;
        Bs[(lj + 1) * 128 + 64 + lrow] = pb1.y;
        Bs[(lj + 2) * 128 + 64 + lrow] = pb1.z;
        Bs[(lj + 3) * 128 + 64 + lrow] = pb1.w;
        __syncthreads();

        const int kk2 = (kk + 16) & (Kd - 1);
        pa0 = *(const float4*)(Ab0 + kk2);
        pa1 = *(const float4*)(Ab1 + kk2);
        pb0 = *(const float4*)(Bb0 + kk2);
        pb1 = *(const float4*)(Bb1 + kk2);

#pragma unroll
        for (int k = 0; k < 16; ++k) {
            const float4 va0 = *(const float4*)&As[k * 128 + (ty << 2)];
            const float4 va1 = *(const float4*)&As[k * 128 + 64 + (ty << 2)];
            const float4 vb0 = *(const float4*)&Bs[k * 128 + (tx << 2)];
            const float4 vb1 = *(const float4*)&Bs[k * 128 + 64 + (tx << 2)];
            const float av[8] = {va0.x, va0.y, va0.z, va0.w,
                                 va1.x, va1.y, va1.z, va1.w};
            const float bv[8] = {vb0.x, vb0.y, vb0.z, vb0.w,
                                 vb1.x, vb1.y, vb1.z, vb1.w};
#pragma unroll
            for (int u = 0; u < 8; ++u)
#pragma unroll
                for (int v = 0; v < 8; ++v) acc[u][v] += av[u] * bv[v];
        }
    }

    const int cn0 = n0 + (tx << 2);
    const float4 p0 = *(const float4*)(b1 + cn0);
    const float4 q0 = *(const float4*)(b2 + cn0);
    const float4 p1 = *(const float4*)(b1 + cn0 + 64);
    const float4 q1 = *(const float4*)(b2 + cn0 + 64);
    const float bias[8] = {p0.x + q0.x, p0.y + q0.y, p0.z + q0.z, p0.w + q0.w,
                           p1.x + q1.x, p1.y + q1.y, p1.z + q1.z, p1.w + q1.w};
#pragma unroll
    for (int u = 0; u < 8; ++u) {
        const int row = m0 + ((u < 4) ? ((ty << 2) + u) : (64 + (ty << 2) + (u - 4)));
        float* Cp = C + (long long)row * Nd;
        *(float4*)(Cp + cn0) =
            make_float4(acc[u][0] + bias[0], acc[u][1] + bias[1],
                        acc[u][2] + bias[2], acc[u][3] + bias[3]);
        *(float4*)(Cp + cn0 + 64) =
            make_float4(acc[u][4] + bias[4], acc[u][5] + bias[5],
                        acc[u][6] + bias[6], acc[u][7] + bias[7]);
    }
}

// ---------------------------------------------------------------------------
// rnn v3: 4 teams (16 batch rows) x 64 WGs (16 cols).  NEW vs v2:
//  - per step, team-h (16 rows x 1024 = 64 KB) is staged into LDS with
//    async global_load_lds (16B x 16 issues/thread, one vmcnt drain at the
//    __syncthreads) instead of 256 latency-exposed global float4 loads per
//    thread inside the fma loop.  Inner loop is now LDS-only.
//  - 4 independent fma accumulator chains (hide 4-cyc fma latency).
//  - only wave 0 polls the team flags (4x less cross-XCD poll traffic).
// Sync/fence protocol identical to v2 (verified): relaxed agent flags,
// release fence by tid0 after syncthreads, acquire fence after poll.
// LDS: Wl 64 KB + hs 64 KB = 128 KB -> 1 WG/CU (unchanged occupancy).
// ---------------------------------------------------------------------------
__global__ __launch_bounds__(256) void rnn_kernel(
    const float* __restrict__ xw, const float* __restrict__ Whh,
    float4* __restrict__ hq,      // [2][256][64] float4
    float* __restrict__ y, float* __restrict__ hlast,
    int* __restrict__ flags)      // [4][64]
{
    __shared__ float4 Wl[4096];   // [k4=256][cl=16]; Wl[k4][cl][j] = Whh[c0+cl][4*k4+j]
    __shared__ float4 hs[4096];   // [k4=256][r_l=16]; staged team h(t)
    const int wid = blockIdx.x;
    const int team = wid >> 6;    // 0..3
    const int m = wid & 63;       // 0..63
    const int c0 = m << 4;
    const int tid = threadIdx.x;
    const int w = tid >> 6;       // wave 0..3
    const int lane = tid & 63;
    const int r_l = lane & 15;
    const int c_lo = lane >> 4;            // 0..3
    const int r = (team << 4) + r_l;       // batch row 0..63
    const int c = c0 + (w << 2) + c_lo;    // hidden col 0..1023

    // Stage W slice into LDS (coalesced along k).
    float* Wlf = (float*)Wl;
    for (int idx = tid; idx < 16384; idx += 256) {
        const int cl = idx >> 10;
        const int k = idx & 1023;
        Wlf[((((k >> 2) << 4) + cl) << 2) + (k & 3)] =
            Whh[(long long)(c0 + cl) * 1024 + k];
    }
    __syncthreads();

    const float* xwp = xw + ((long long)r << 19) + c;   // r*512*1024 + c
    float* yp = y + ((long long)r << 19) + c;
    int* tflags = flags + (team << 6);
    const float4* __restrict__ wc = Wl + (w << 2) + c_lo;  // + k4*16
    const float4* __restrict__ hr = hs + r_l;              // + k4*16
    const int pq = ((c >> 2) << 6) + r;                 // producer float4 index
    const int pc = c & 3;
    // per-thread source base for the team-h stage (float4 units):
    // covers (k4 = tid>>4 + 16*i, row = team*16 + (tid&15)) for i = 0..15
    const int gsb = ((tid >> 4) << 6) + (team << 4) + (tid & 15);

    float xw_cur = xwp[0];

    for (int t = 0; t < 512; ++t) {
        // prefetch next xw before the barrier wait (overlaps poll latency)
        float xw_next = (t < 511) ? xwp[(long long)(t + 1) << 10] : 0.f;

        if (t > 0) {
            // wave 0 waits until all 64 team producers have published h(t)
            if (w == 0) {
                while (true) {
                    int f = FLAG_LD(tflags + lane);
                    if (__all(f >= t)) break;
                }
            }
            __syncthreads();
            __threadfence();   // acquire: invalidate stale cached h lines
        }

        // --- async stage of team h(t) into LDS: 16 x 16B per thread ---
        {
            const float4* gb = hq + ((t & 1) << 14) + gsb;
#pragma unroll
            for (int i = 0; i < 16; ++i) {
                __builtin_amdgcn_global_load_lds(
                    (const __attribute__((address_space(1))) void*)(gb + (i << 10)),
                    (__attribute__((address_space(3))) void*)(hs + tid + (i << 8)),
                    16, 0, 0);
            }
        }
        __syncthreads();   // drains vmcnt (stage complete) + barrier

        // --- LDS-only dot product, 4 independent fma chains ---
        float4 a0 = make_float4(xw_cur, 0.f, 0.f, 0.f);
        float4 a1 = make_float4(0.f, 0.f, 0.f, 0.f);
        float4 a2 = a1, a3 = a1;
#pragma unroll 2
        for (int k4 = 0; k4 < 256; k4 += 4) {
            const float4 h0 = hr[(k4 + 0) << 4];
            const float4 w0 = wc[(k4 + 0) << 4];
            const float4 h1 = hr[(k4 + 1) << 4];
            const float4 w1 = wc[(k4 + 1) << 4];
            const float4 h2 = hr[(k4 + 2) << 4];
            const float4 w2 = wc[(k4 + 2) << 4];
            const float4 h3 = hr[(k4 + 3) << 4];
            const float4 w3 = wc[(k4 + 3) << 4];
            a0.x = fmaf(w0.x, h0.x, a0.x);
            a0.y = fmaf(w0.y, h0.y, a0.y);
            a0.z = fmaf(w0.z, h0.z, a0.z);
            a0.w = fmaf(w0.w, h0.w, a0.w);
            a1.x = fmaf(w1.x, h1.x, a1.x);
            a1.y = fmaf(w1.y, h1.y, a1.y);
            a1.z = fmaf(w1.z, h1.z, a1.z);
            a1.w = fmaf(w1.w, h1.w, a1.w);
            a2.x = fmaf(w2.x, h2.x, a2.x);
            a2.y = fmaf(w2.y, h2.y, a2.y);
            a2.z = fmaf(w2.z, h2.z, a2.z);
            a2.w = fmaf(w2.w, h2.w, a2.w);
            a3.x = fmaf(w3.x, h3.x, a3.x);
            a3.y = fmaf(w3.y, h3.y, a3.y);
            a3.z = fmaf(w3.z, h3.z, a3.z);
            a3.w = fmaf(w3.w, h3.w, a3.w);
        }
        const float s =
            (((a0.x + a1.x) + (a2.x + a3.x)) + ((a0.y + a1.y) + (a2.y + a3.y))) +
            (((a0.z + a1.z) + (a2.z + a3.z)) + ((a0.w + a1.w) + (a2.w + a3.w)));
        const float hn = tanhf(s);

        // publish h(t+1) (k-transposed, coalesced) + y
        float* hqs = (float*)(hq + (((t + 1) & 1) << 14));
        hqs[(pq << 2) + pc] = hn;
        yp[(long long)t << 10] = hn;
        if (t == 511) hlast[(r << 10) + c] = hn;

        __syncthreads();                 // drains WG stores (vmcnt) to L2
        if (tid == 0) {
            __threadfence();             // release: push to agent scope
            FLAG_ST(tflags + m, t + 1);
        }
        xw_cur = xw_next;
    }
}

// ---------------------------------------------------------------------------
extern "C" void kernel_launch(void* const* d_in, const int* in_sizes, int n_in,
                              void* d_out, int out_size, void* d_ws, size_t ws_size,
                              hipStream_t stream)
{
    const float* X    = (const float*)d_in[0];
    const float* Wih0 = (const float*)d_in[1];
    const float* bih0 = (const float*)d_in[2];
    const float* Whh0 = (const float*)d_in[3];
    const float* bhh0 = (const float*)d_in[4];
    const float* Wih1 = (const float*)d_in[5];
    const float* bih1 = (const float*)d_in[6];
    const float* Whh1 = (const float*)d_in[7];
    const float* bhh1 = (const float*)d_in[8];

    float* y     = (float*)d_out;          // [64,512,1024]
    float* hlast = y + 33554432ll;         // [2,64,1024]
    float* xw    = (float*)d_ws;           // [64,512,1024]
    float4* hq   = (float4*)(xw + 33554432ll);       // [2][256][64] float4 = 512 KB
    int* flags   = (int*)(hq + 32768);               // [4][64] = 1 KB

    const dim3 pgrid(8, 256), pblock(256);
    const dim3 rgrid(256), rblock(256);

    // ---- layer 0 ----
    hipMemsetAsync(hq, 0, 32768 * sizeof(float4), stream);
    hipMemsetAsync(flags, 0, 256 * sizeof(int), stream);
    hipLaunchKernelGGL(proj_kernel, pgrid, pblock, 0, stream,
                       X, Wih0, bih0, bhh0, xw);
    {
        const float* xw_c = xw;
        float* hl0 = hlast;
        void* args0[] = {(void*)&xw_c, (void*)&Whh0, (void*)&hq,
                         (void*)&y, (void*)&hl0, (void*)&flags};
        hipLaunchCooperativeKernel((void*)rnn_kernel, rgrid, rblock, args0, 0, stream);
    }

    // ---- layer 1 ----
    hipMemsetAsync(hq, 0, 32768 * sizeof(float4), stream);
    hipMemsetAsync(flags, 0, 256 * sizeof(int), stream);
    hipLaunchKernelGGL(proj_kernel, pgrid, pblock, 0, stream,
                       (const float*)y, Wih1, bih1, bhh1, xw);
    {
        const float* xw_c = xw;
        float* hl1 = hlast + 65536;
        void* args1[] = {(void*)&xw_c, (void*)&Whh1, (void*)&hq,
                         (void*)&y, (void*)&hl1, (void*)&flags};
        hipLaunchCooperativeKernel((void*)rnn_kernel, rgrid, rblock, args1, 0, stream);
    }
}

// Round 3
// 19540.994 us; speedup vs baseline: 1.9640x; 1.7977x over previous
//
#include <hip/hip_runtime.h>
#include <hip/hip_cooperative_groups.h>

namespace cg = cooperative_groups;

// Problem constants: B=64, T=512, I=H=1024, L=2  (all fp32)
// d_out = y [64,512,1024] ++ h_last [2,64,1024]
// d_ws  = xw [64,512,1024] ++ hq [2][256][64] float4 ++ flags [4*64] int

#define FLAG_LD(p)    __hip_atomic_load((p), __ATOMIC_RELAXED, __HIP_MEMORY_SCOPE_AGENT)
#define FLAG_ST(p, v) __hip_atomic_store((p), (v), __ATOMIC_RELAXED, __HIP_MEMORY_SCOPE_AGENT)

// ---------------------------------------------------------------------------
// proj: C[M,1024] = A[M,1024] @ W[1024,1024]^T + (b1 + b2)
// 128x128 tile, 256 threads, 8x8 micro-tile, BK=16, global prefetch.
// (unchanged)
// ---------------------------------------------------------------------------
__global__ __launch_bounds__(256) void proj_kernel(
    const float* __restrict__ A, const float* __restrict__ W,
    const float* __restrict__ b1, const float* __restrict__ b2,
    float* __restrict__ C)
{
    constexpr int Kd = 1024;
    constexpr int Nd = 1024;
    const int n0 = blockIdx.x * 128;
    const int m0 = blockIdx.y * 128;
    __shared__ float As[16 * 128];
    __shared__ float Bs[16 * 128];
    const int tid = threadIdx.x;
    const int tx = tid & 15;
    const int ty = tid >> 4;
    const int lrow = tid >> 2;
    const int lj = (tid & 3) << 2;

    float acc[8][8];
#pragma unroll
    for (int u = 0; u < 8; ++u)
#pragma unroll
        for (int v = 0; v < 8; ++v) acc[u][v] = 0.f;

    const float* Ab0 = A + (long long)(m0 + lrow) * Kd + lj;
    const float* Ab1 = Ab0 + 64ll * Kd;
    const float* Bb0 = W + (long long)(n0 + lrow) * Kd + lj;
    const float* Bb1 = Bb0 + 64ll * Kd;

    float4 pa0 = *(const float4*)(Ab0);
    float4 pa1 = *(const float4*)(Ab1);
    float4 pb0 = *(const float4*)(Bb0);
    float4 pb1 = *(const float4*)(Bb1);

    for (int kk = 0; kk < Kd; kk += 16) {
        __syncthreads();
        As[(lj + 0) * 128 + lrow] = pa0.x;
        As[(lj + 1) * 128 + lrow] = pa0.y;
        As[(lj + 2) * 128 + lrow] = pa0.z;
        As[(lj + 3) * 128 + lrow] = pa0.w;
        As[(lj + 0) * 128 + 64 + lrow] = pa1.x;
        As[(lj + 1) * 128 + 64 + lrow] = pa1.y;
        As[(lj + 2) * 128 + 64 + lrow] = pa1.z;
        As[(lj + 3) * 128 + 64 + lrow] = pa1.w;
        Bs[(lj + 0) * 128 + lrow] = pb0.x;
        Bs[(lj + 1) * 128 + lrow] = pb0.y;
        Bs[(lj + 2) * 128 + lrow] = pb0.z;
        Bs[(lj + 3) * 128 + lrow] = pb0.w;
        Bs[(lj + 0) * 128 + 64 + lrow] = pb1.x;
        Bs[(lj + 1) * 128 + 64 + lrow] = pb1.y;
        Bs[(lj + 2) * 128 + 64 + lrow] = pb1.z;
        Bs[(lj + 3) * 128 + 64 + lrow] = pb1.w;
        __syncthreads();

        const int kk2 = (kk + 16) & (Kd - 1);
        pa0 = *(const float4*)(Ab0 + kk2);
        pa1 = *(const float4*)(Ab1 + kk2);
        pb0 = *(const float4*)(Bb0 + kk2);
        pb1 = *(const float4*)(Bb1 + kk2);

#pragma unroll
        for (int k = 0; k < 16; ++k) {
            const float4 va0 = *(const float4*)&As[k * 128 + (ty << 2)];
            const float4 va1 = *(const float4*)&As[k * 128 + 64 + (ty << 2)];
            const float4 vb0 = *(const float4*)&Bs[k * 128 + (tx << 2)];
            const float4 vb1 = *(const float4*)&Bs[k * 128 + 64 + (tx << 2)];
            const float av[8] = {va0.x, va0.y, va0.z, va0.w,
                                 va1.x, va1.y, va1.z, va1.w};
            const float bv[8] = {vb0.x, vb0.y, vb0.z, vb0.w,
                                 vb1.x, vb1.y, vb1.z, vb1.w};
#pragma unroll
            for (int u = 0; u < 8; ++u)
#pragma unroll
                for (int v = 0; v < 8; ++v) acc[u][v] += av[u] * bv[v];
        }
    }

    const int cn0 = n0 + (tx << 2);
    const float4 p0 = *(const float4*)(b1 + cn0);
    const float4 q0 = *(const float4*)(b2 + cn0);
    const float4 p1 = *(const float4*)(b1 + cn0 + 64);
    const float4 q1 = *(const float4*)(b2 + cn0 + 64);
    const float bias[8] = {p0.x + q0.x, p0.y + q0.y, p0.z + q0.z, p0.w + q0.w,
                           p1.x + q1.x, p1.y + q1.y, p1.z + q1.z, p1.w + q1.w};
#pragma unroll
    for (int u = 0; u < 8; ++u) {
        const int row = m0 + ((u < 4) ? ((ty << 2) + u) : (64 + (ty << 2) + (u - 4)));
        float* Cp = C + (long long)row * Nd;
        *(float4*)(Cp + cn0) =
            make_float4(acc[u][0] + bias[0], acc[u][1] + bias[1],
                        acc[u][2] + bias[2], acc[u][3] + bias[3]);
        *(float4*)(Cp + cn0 + 64) =
            make_float4(acc[u][4] + bias[4], acc[u][5] + bias[5],
                        acc[u][6] + bias[6], acc[u][7] + bias[7]);
    }
}

// ---------------------------------------------------------------------------
// rnn v5: identical protocol SEMANTICS to v3 (verified), cheaper fences:
//  - v3 used __threadfence() = seq_cst fence = buffer_wbl2 + buffer_inv,
//    executed by ALL 4 waves on acquire + tid0 on release
//    -> ~5 wbl2 + 5 inv per WG per step (~160 whole-cache ops/XCD/step).
//  - v5 acquire: ONE fence(acquire,"agent") in wave 0 only (waitcnt +
//    buffer_inv), then explicit s_waitcnt vmcnt(0) so the inv is complete
//    before ANY wave crosses the barrier.  L1 is CU-wide and L2 is
//    XCD-wide, so one wave's inv covers the whole WG.
//  - v5 release: fence(release,"agent") in tid0 (waitcnt + buffer_wbl2 +
//    waitcnt), i.e. no useless inv on the producer side.
//  - y/hlast stores are non-temporal: they no longer dirty the L2, so the
//    per-step wbl2 only writes back the WG's 4 KB of h.
//  -> 1 wbl2 + 1 inv per WG per step, wbl2 nearly empty.
// Data path identical to v3: LDS-staged h via global_load_lds (aux=0),
// LDS-only fma loop, double-buffered hq, generation flags, wave-0 poll.
// LDS: Wl 64 KB + hs 64 KB = 128 KB -> 1 WG/CU.
// ---------------------------------------------------------------------------
__global__ __launch_bounds__(256) void rnn_kernel(
    const float* __restrict__ xw, const float* __restrict__ Whh,
    float4* __restrict__ hq,      // [2][256][64] float4
    float* __restrict__ y, float* __restrict__ hlast,
    int* __restrict__ flags)      // [4][64]
{
    __shared__ float4 Wl[4096];   // [k4=256][cl=16]; Wl[k4][cl][j] = Whh[c0+cl][4*k4+j]
    __shared__ float4 hs[4096];   // [k4=256][r_l=16]; staged team h(t)
    const int wid = blockIdx.x;
    const int team = wid >> 6;    // 0..3
    const int m = wid & 63;       // 0..63
    const int c0 = m << 4;
    const int tid = threadIdx.x;
    const int w = tid >> 6;       // wave 0..3
    const int lane = tid & 63;
    const int r_l = lane & 15;
    const int c_lo = lane >> 4;            // 0..3
    const int r = (team << 4) + r_l;       // batch row 0..63
    const int c = c0 + (w << 2) + c_lo;    // hidden col 0..1023

    // Stage W slice into LDS (coalesced along k).
    float* Wlf = (float*)Wl;
    for (int idx = tid; idx < 16384; idx += 256) {
        const int cl = idx >> 10;
        const int k = idx & 1023;
        Wlf[((((k >> 2) << 4) + cl) << 2) + (k & 3)] =
            Whh[(long long)(c0 + cl) * 1024 + k];
    }
    __syncthreads();

    const float* xwp = xw + ((long long)r << 19) + c;   // r*512*1024 + c
    float* yp = y + ((long long)r << 19) + c;
    int* tflags = flags + (team << 6);
    const float4* __restrict__ wc = Wl + (w << 2) + c_lo;  // + k4*16
    const float4* __restrict__ hr = hs + r_l;              // + k4*16
    const int pq = ((c >> 2) << 6) + r;                 // producer float4 index
    const int pc = c & 3;
    // per-thread source base for the team-h stage (float4 units):
    // covers (k4 = tid>>4 + 16*i, row = team*16 + (tid&15)) for i = 0..15
    const int gsb = ((tid >> 4) << 6) + (team << 4) + (tid & 15);

    float xw_cur = xwp[0];

    for (int t = 0; t < 512; ++t) {
        // prefetch next xw before the barrier wait (overlaps poll latency)
        float xw_next = (t < 511) ? xwp[(long long)(t + 1) << 10] : 0.f;

        if (t > 0) {
            // wave 0: wait until all 64 team producers published h(t),
            // then ONE acquire fence (buffer_inv) for the whole WG and an
            // explicit vmcnt drain so the inv is complete before the
            // barrier releases the other waves' stage loads.
            if (w == 0) {
                while (true) {
                    int f = FLAG_LD(tflags + lane);
                    if (__all(f >= t)) break;
                }
                __builtin_amdgcn_fence(__ATOMIC_ACQUIRE, "agent");
                asm volatile("s_waitcnt vmcnt(0)" ::: "memory");
            }
            __syncthreads();
        }

        // --- async stage of team h(t) into LDS: 16 x 16B per thread ---
        {
            const float4* gb = hq + ((t & 1) << 14) + gsb;
#pragma unroll
            for (int i = 0; i < 16; ++i) {
                __builtin_amdgcn_global_load_lds(
                    (const __attribute__((address_space(1))) void*)(gb + (i << 10)),
                    (__attribute__((address_space(3))) void*)(hs + tid + (i << 8)),
                    16, 0, 0);
            }
        }
        __syncthreads();   // drains vmcnt (stage complete) + barrier

        // --- LDS-only dot product, 4 independent fma chains ---
        float4 a0 = make_float4(xw_cur, 0.f, 0.f, 0.f);
        float4 a1 = make_float4(0.f, 0.f, 0.f, 0.f);
        float4 a2 = a1, a3 = a1;
#pragma unroll 2
        for (int k4 = 0; k4 < 256; k4 += 4) {
            const float4 h0 = hr[(k4 + 0) << 4];
            const float4 w0 = wc[(k4 + 0) << 4];
            const float4 h1 = hr[(k4 + 1) << 4];
            const float4 w1 = wc[(k4 + 1) << 4];
            const float4 h2 = hr[(k4 + 2) << 4];
            const float4 w2 = wc[(k4 + 2) << 4];
            const float4 h3 = hr[(k4 + 3) << 4];
            const float4 w3 = wc[(k4 + 3) << 4];
            a0.x = fmaf(w0.x, h0.x, a0.x);
            a0.y = fmaf(w0.y, h0.y, a0.y);
            a0.z = fmaf(w0.z, h0.z, a0.z);
            a0.w = fmaf(w0.w, h0.w, a0.w);
            a1.x = fmaf(w1.x, h1.x, a1.x);
            a1.y = fmaf(w1.y, h1.y, a1.y);
            a1.z = fmaf(w1.z, h1.z, a1.z);
            a1.w = fmaf(w1.w, h1.w, a1.w);
            a2.x = fmaf(w2.x, h2.x, a2.x);
            a2.y = fmaf(w2.y, h2.y, a2.y);
            a2.z = fmaf(w2.z, h2.z, a2.z);
            a2.w = fmaf(w2.w, h2.w, a2.w);
            a3.x = fmaf(w3.x, h3.x, a3.x);
            a3.y = fmaf(w3.y, h3.y, a3.y);
            a3.z = fmaf(w3.z, h3.z, a3.z);
            a3.w = fmaf(w3.w, h3.w, a3.w);
        }
        const float s =
            (((a0.x + a1.x) + (a2.x + a3.x)) + ((a0.y + a1.y) + (a2.y + a3.y))) +
            (((a0.z + a1.z) + (a2.z + a3.z)) + ((a0.w + a1.w) + (a2.w + a3.w)));
        const float hn = tanhf(s);

        // publish h(t+1) (k-transposed, coalesced); y/hlast non-temporal so
        // they never dirty the L2 (keeps the release wbl2 nearly empty).
        float* hqs = (float*)(hq + (((t + 1) & 1) << 14));
        hqs[(pq << 2) + pc] = hn;
        __builtin_nontemporal_store(hn, yp + ((long long)t << 10));
        if (t == 511)
            __builtin_nontemporal_store(hn, hlast + (r << 10) + c);

        __syncthreads();                 // vmcnt(0) drain: h stores in L2
        if (tid == 0) {
            // release: write back this XCD's dirty h lines to IC, then flag
            __builtin_amdgcn_fence(__ATOMIC_RELEASE, "agent");
            FLAG_ST(tflags + m, t + 1);
        }
        xw_cur = xw_next;
    }
}

// ---------------------------------------------------------------------------
extern "C" void kernel_launch(void* const* d_in, const int* in_sizes, int n_in,
                              void* d_out, int out_size, void* d_ws, size_t ws_size,
                              hipStream_t stream)
{
    const float* X    = (const float*)d_in[0];
    const float* Wih0 = (const float*)d_in[1];
    const float* bih0 = (const float*)d_in[2];
    const float* Whh0 = (const float*)d_in[3];
    const float* bhh0 = (const float*)d_in[4];
    const float* Wih1 = (const float*)d_in[5];
    const float* bih1 = (const float*)d_in[6];
    const float* Whh1 = (const float*)d_in[7];
    const float* bhh1 = (const float*)d_in[8];

    float* y     = (float*)d_out;          // [64,512,1024]
    float* hlast = y + 33554432ll;         // [2,64,1024]
    float* xw    = (float*)d_ws;           // [64,512,1024]
    float4* hq   = (float4*)(xw + 33554432ll);       // [2][256][64] float4 = 512 KB
    int* flags   = (int*)(hq + 32768);               // [4][64] = 1 KB

    const dim3 pgrid(8, 256), pblock(256);
    const dim3 rgrid(256), rblock(256);

    // ---- layer 0 ----
    hipMemsetAsync(hq, 0, 32768 * sizeof(float4), stream);
    hipMemsetAsync(flags, 0, 256 * sizeof(int), stream);
    hipLaunchKernelGGL(proj_kernel, pgrid, pblock, 0, stream,
                       X, Wih0, bih0, bhh0, xw);
    {
        const float* xw_c = xw;
        float* hl0 = hlast;
        void* args0[] = {(void*)&xw_c, (void*)&Whh0, (void*)&hq,
                         (void*)&y, (void*)&hl0, (void*)&flags};
        hipLaunchCooperativeKernel((void*)rnn_kernel, rgrid, rblock, args0, 0, stream);
    }

    // ---- layer 1 ----
    hipMemsetAsync(hq, 0, 32768 * sizeof(float4), stream);
    hipMemsetAsync(flags, 0, 256 * sizeof(int), stream);
    hipLaunchKernelGGL(proj_kernel, pgrid, pblock, 0, stream,
                       (const float*)y, Wih1, bih1, bhh1, xw);
    {
        const float* xw_c = xw;
        float* hl1 = hlast + 65536;
        void* args1[] = {(void*)&xw_c, (void*)&Whh1, (void*)&hq,
                         (void*)&y, (void*)&hl1, (void*)&flags};
        hipLaunchCooperativeKernel((void*)rnn_kernel, rgrid, rblock, args1, 0, stream);
    }
}

// Round 5
// 19128.644 us; speedup vs baseline: 2.0063x; 1.0216x over previous
//
#include <hip/hip_runtime.h>
#include <hip/hip_cooperative_groups.h>

namespace cg = cooperative_groups;

// Problem constants: B=64, T=512, I=H=1024, L=2  (all fp32)
// d_out = y [64,512,1024] ++ h_last [2,64,1024]
// d_ws  = xw [64,512,1024] ++ hq [2][256][64] float4 ++ flags [4*64] int

#define FLAG_LD(p)    __hip_atomic_load((p), __ATOMIC_RELAXED, __HIP_MEMORY_SCOPE_AGENT)
#define FLAG_ST(p, v) __hip_atomic_store((p), (v), __ATOMIC_RELAXED, __HIP_MEMORY_SCOPE_AGENT)
#define H_LD64(p)     __hip_atomic_load((p), __ATOMIC_RELAXED, __HIP_MEMORY_SCOPE_AGENT)

// ---------------------------------------------------------------------------
// proj: C[M,1024] = A[M,1024] @ W[1024,1024]^T + (b1 + b2)
// 128x128 tile, 256 threads, 8x8 micro-tile, BK=16, global prefetch.
// (unchanged)
// ---------------------------------------------------------------------------
__global__ __launch_bounds__(256) void proj_kernel(
    const float* __restrict__ A, const float* __restrict__ W,
    const float* __restrict__ b1, const float* __restrict__ b2,
    float* __restrict__ C)
{
    constexpr int Kd = 1024;
    constexpr int Nd = 1024;
    const int n0 = blockIdx.x * 128;
    const int m0 = blockIdx.y * 128;
    __shared__ float As[16 * 128];
    __shared__ float Bs[16 * 128];
    const int tid = threadIdx.x;
    const int tx = tid & 15;
    const int ty = tid >> 4;
    const int lrow = tid >> 2;
    const int lj = (tid & 3) << 2;

    float acc[8][8];
#pragma unroll
    for (int u = 0; u < 8; ++u)
#pragma unroll
        for (int v = 0; v < 8; ++v) acc[u][v] = 0.f;

    const float* Ab0 = A + (long long)(m0 + lrow) * Kd + lj;
    const float* Ab1 = Ab0 + 64ll * Kd;
    const float* Bb0 = W + (long long)(n0 + lrow) * Kd + lj;
    const float* Bb1 = Bb0 + 64ll * Kd;

    float4 pa0 = *(const float4*)(Ab0);
    float4 pa1 = *(const float4*)(Ab1);
    float4 pb0 = *(const float4*)(Bb0);
    float4 pb1 = *(const float4*)(Bb1);

    for (int kk = 0; kk < Kd; kk += 16) {
        __syncthreads();
        As[(lj + 0) * 128 + lrow] = pa0.x;
        As[(lj + 1) * 128 + lrow] = pa0.y;
        As[(lj + 2) * 128 + lrow] = pa0.z;
        As[(lj + 3) * 128 + lrow] = pa0.w;
        As[(lj + 0) * 128 + 64 + lrow] = pa1.x;
        As[(lj + 1) * 128 + 64 + lrow] = pa1.y;
        As[(lj + 2) * 128 + 64 + lrow] = pa1.z;
        As[(lj + 3) * 128 + 64 + lrow] = pa1.w;
        Bs[(lj + 0) * 128 + lrow] = pb0.x;
        Bs[(lj + 1) * 128 + lrow] = pb0.y;
        Bs[(lj + 2) * 128 + lrow] = pb0.z;
        Bs[(lj + 3) * 128 + lrow] = pb0.w;
        Bs[(lj + 0) * 128 + 64 + lrow] = pb1.x;
        Bs[(lj + 1) * 128 + 64 + lrow] = pb1.y;
        Bs[(lj + 2) * 128 + 64 + lrow] = pb1.z;
        Bs[(lj + 3) * 128 + 64 + lrow] = pb1.w;
        __syncthreads();

        const int kk2 = (kk + 16) & (Kd - 1);
        pa0 = *(const float4*)(Ab0 + kk2);
        pa1 = *(const float4*)(Ab1 + kk2);
        pb0 = *(const float4*)(Bb0 + kk2);
        pb1 = *(const float4*)(Bb1 + kk2);

#pragma unroll
        for (int k = 0; k < 16; ++k) {
            const float4 va0 = *(const float4*)&As[k * 128 + (ty << 2)];
            const float4 va1 = *(const float4*)&As[k * 128 + 64 + (ty << 2)];
            const float4 vb0 = *(const float4*)&Bs[k * 128 + (tx << 2)];
            const float4 vb1 = *(const float4*)&Bs[k * 128 + 64 + (tx << 2)];
            const float av[8] = {va0.x, va0.y, va0.z, va0.w,
                                 va1.x, va1.y, va1.z, va1.w};
            const float bv[8] = {vb0.x, vb0.y, vb0.z, vb0.w,
                                 vb1.x, vb1.y, vb1.z, vb1.w};
#pragma unroll
            for (int u = 0; u < 8; ++u)
#pragma unroll
                for (int v = 0; v < 8; ++v) acc[u][v] += av[u] * bv[v];
        }
    }

    const int cn0 = n0 + (tx << 2);
    const float4 p0 = *(const float4*)(b1 + cn0);
    const float4 q0 = *(const float4*)(b2 + cn0);
    const float4 p1 = *(const float4*)(b1 + cn0 + 64);
    const float4 q1 = *(const float4*)(b2 + cn0 + 64);
    const float bias[8] = {p0.x + q0.x, p0.y + q0.y, p0.z + q0.z, p0.w + q0.w,
                           p1.x + q1.x, p1.y + q1.y, p1.z + q1.z, p1.w + q1.w};
#pragma unroll
    for (int u = 0; u < 8; ++u) {
        const int row = m0 + ((u < 4) ? ((ty << 2) + u) : (64 + (ty << 2) + (u - 4)));
        float* Cp = C + (long long)row * Nd;
        *(float4*)(Cp + cn0) =
            make_float4(acc[u][0] + bias[0], acc[u][1] + bias[1],
                        acc[u][2] + bias[2], acc[u][3] + bias[3]);
        *(float4*)(Cp + cn0 + 64) =
            make_float4(acc[u][4] + bias[4], acc[u][5] + bias[5],
                        acc[u][6] + bias[6], acc[u][7] + bias[7]);
    }
}

// ---------------------------------------------------------------------------
// rnn v6b: v5 with the acquire-side whole-cache invalidate removed, using
// the PROVEN per-access coherent mechanism (NOT v6's inline asm):
//  - stage loads = __hip_atomic_load(u64, RELAXED, AGENT) — exactly the
//    instruction class the (verified, terminating) flag polls use.  Since
//    the v5 poll observes remote flag updates without any fence, these
//    loads observe the remote h data that the producer's release-wbl2
//    (kept, verified) pushed to the coherence point.
//  - acquire fence + vmcnt hack: DELETED (no more whole-L1/L2 invalidate
//    per WG per step; xw/W lines now survive in L2 across steps).
//  - producer/release side byte-identical to v5 (verified): plain h
//    stores -> __syncthreads drain -> tid0 fence(release,agent) -> flag.
//  - stage: 32 x 8B coherent loads/thread into a fully-unrolled register
//    array (static indices -> registers, no scratch), then LDS writes.
// LDS: Wl 64 KB + hs 64 KB = 128 KB -> 1 WG/CU.
// ---------------------------------------------------------------------------
__global__ __launch_bounds__(256) void rnn_kernel(
    const float* __restrict__ xw, const float* __restrict__ Whh,
    float4* __restrict__ hq,      // [2][256][64] float4
    float* __restrict__ y, float* __restrict__ hlast,
    int* __restrict__ flags)      // [4][64]
{
    __shared__ float4 Wl[4096];   // [k4=256][cl=16]; Wl[k4][cl][j] = Whh[c0+cl][4*k4+j]
    __shared__ float4 hs[4096];   // [k4=256][r_l=16]; staged team h(t)
    const int wid = blockIdx.x;
    const int team = wid >> 6;    // 0..3
    const int m = wid & 63;       // 0..63
    const int c0 = m << 4;
    const int tid = threadIdx.x;
    const int w = tid >> 6;       // wave 0..3
    const int lane = tid & 63;
    const int r_l = lane & 15;
    const int c_lo = lane >> 4;            // 0..3
    const int r = (team << 4) + r_l;       // batch row 0..63
    const int c = c0 + (w << 2) + c_lo;    // hidden col 0..1023

    // Stage W slice into LDS (coalesced along k).
    float* Wlf = (float*)Wl;
    for (int idx = tid; idx < 16384; idx += 256) {
        const int cl = idx >> 10;
        const int k = idx & 1023;
        Wlf[((((k >> 2) << 4) + cl) << 2) + (k & 3)] =
            Whh[(long long)(c0 + cl) * 1024 + k];
    }
    __syncthreads();

    const float* xwp = xw + ((long long)r << 19) + c;   // r*512*1024 + c
    float* yp = y + ((long long)r << 19) + c;
    int* tflags = flags + (team << 6);
    const float4* __restrict__ wc = Wl + (w << 2) + c_lo;  // + k4*16
    const float4* __restrict__ hr = hs + r_l;              // + k4*16
    const int pq = ((c >> 2) << 6) + r;                 // producer float4 index
    const int pc = c & 3;
    // per-thread source base for the team-h stage (float4 units):
    // covers (k4 = tid>>4 + 16*i, row = team*16 + (tid&15)) for i = 0..15
    const int gsb = ((tid >> 4) << 6) + (team << 4) + (tid & 15);

    float xw_cur = xwp[0];

    for (int t = 0; t < 512; ++t) {
        // prefetch next xw before the barrier wait (overlaps poll latency)
        float xw_next = (t < 511) ? xwp[(long long)(t + 1) << 10] : 0.f;

        if (t > 0) {
            // wave 0: wait until all 64 team producers published h(t).
            // No acquire fence: stage loads below are per-access coherent.
            if (w == 0) {
                while (true) {
                    int f = FLAG_LD(tflags + lane);
                    if (__all(f >= t)) break;
                }
            }
            __syncthreads();
        }

        // --- stage team h(t) into LDS: 32 x 8B agent-coherent loads per
        //     thread (same mechanism as the flag polls), then LDS writes ---
        {
            const unsigned long long* g64 =
                (const unsigned long long*)(hq + ((t & 1) << 14));
            unsigned long long v[32];
#pragma unroll
            for (int i = 0; i < 16; ++i) {
                const int fi = (gsb + (i << 10)) << 1;   // u64 index
                v[2 * i]     = H_LD64(g64 + fi);
                v[2 * i + 1] = H_LD64(g64 + fi + 1);
            }
#pragma unroll
            for (int i = 0; i < 16; ++i) {
                unsigned long long* d =
                    (unsigned long long*)&hs[tid + (i << 8)];
                d[0] = v[2 * i];
                d[1] = v[2 * i + 1];
            }
        }
        __syncthreads();   // drains lgkmcnt (ds_writes) + barrier

        // --- LDS-only dot product, 4 independent fma chains ---
        float4 a0 = make_float4(xw_cur, 0.f, 0.f, 0.f);
        float4 a1 = make_float4(0.f, 0.f, 0.f, 0.f);
        float4 a2 = a1, a3 = a1;
#pragma unroll 2
        for (int k4 = 0; k4 < 256; k4 += 4) {
            const float4 h0 = hr[(k4 + 0) << 4];
            const float4 w0 = wc[(k4 + 0) << 4];
            const float4 h1 = hr[(k4 + 1) << 4];
            const float4 w1 = wc[(k4 + 1) << 4];
            const float4 h2 = hr[(k4 + 2) << 4];
            const float4 w2 = wc[(k4 + 2) << 4];
            const float4 h3 = hr[(k4 + 3) << 4];
            const float4 w3 = wc[(k4 + 3) << 4];
            a0.x = fmaf(w0.x, h0.x, a0.x);
            a0.y = fmaf(w0.y, h0.y, a0.y);
            a0.z = fmaf(w0.z, h0.z, a0.z);
            a0.w = fmaf(w0.w, h0.w, a0.w);
            a1.x = fmaf(w1.x, h1.x, a1.x);
            a1.y = fmaf(w1.y, h1.y, a1.y);
            a1.z = fmaf(w1.z, h1.z, a1.z);
            a1.w = fmaf(w1.w, h1.w, a1.w);
            a2.x = fmaf(w2.x, h2.x, a2.x);
            a2.y = fmaf(w2.y, h2.y, a2.y);
            a2.z = fmaf(w2.z, h2.z, a2.z);
            a2.w = fmaf(w2.w, h2.w, a2.w);
            a3.x = fmaf(w3.x, h3.x, a3.x);
            a3.y = fmaf(w3.y, h3.y, a3.y);
            a3.z = fmaf(w3.z, h3.z, a3.z);
            a3.w = fmaf(w3.w, h3.w, a3.w);
        }
        const float s =
            (((a0.x + a1.x) + (a2.x + a3.x)) + ((a0.y + a1.y) + (a2.y + a3.y))) +
            (((a0.z + a1.z) + (a2.z + a3.z)) + ((a0.w + a1.w) + (a2.w + a3.w)));
        const float hn = tanhf(s);

        // publish h(t+1) (k-transposed, coalesced); y/hlast non-temporal so
        // they never dirty the L2 (keeps the release wbl2 nearly empty).
        float* hqs = (float*)(hq + (((t + 1) & 1) << 14));
        hqs[(pq << 2) + pc] = hn;
        __builtin_nontemporal_store(hn, yp + ((long long)t << 10));
        if (t == 511)
            __builtin_nontemporal_store(hn, hlast + (r << 10) + c);

        __syncthreads();                 // vmcnt(0) drain: h stores in L2
        if (tid == 0) {
            // release: write back this XCD's dirty h lines, then flag
            __builtin_amdgcn_fence(__ATOMIC_RELEASE, "agent");
            FLAG_ST(tflags + m, t + 1);
        }
        xw_cur = xw_next;
    }
}

// ---------------------------------------------------------------------------
extern "C" void kernel_launch(void* const* d_in, const int* in_sizes, int n_in,
                              void* d_out, int out_size, void* d_ws, size_t ws_size,
                              hipStream_t stream)
{
    const float* X    = (const float*)d_in[0];
    const float* Wih0 = (const float*)d_in[1];
    const float* bih0 = (const float*)d_in[2];
    const float* Whh0 = (const float*)d_in[3];
    const float* bhh0 = (const float*)d_in[4];
    const float* Wih1 = (const float*)d_in[5];
    const float* bih1 = (const float*)d_in[6];
    const float* Whh1 = (const float*)d_in[7];
    const float* bhh1 = (const float*)d_in[8];

    float* y     = (float*)d_out;          // [64,512,1024]
    float* hlast = y + 33554432ll;         // [2,64,1024]
    float* xw    = (float*)d_ws;           // [64,512,1024]
    float4* hq   = (float4*)(xw + 33554432ll);       // [2][256][64] float4 = 512 KB
    int* flags   = (int*)(hq + 32768);               // [4][64] = 1 KB

    const dim3 pgrid(8, 256), pblock(256);
    const dim3 rgrid(256), rblock(256);

    // ---- layer 0 ----
    hipMemsetAsync(hq, 0, 32768 * sizeof(float4), stream);
    hipMemsetAsync(flags, 0, 256 * sizeof(int), stream);
    hipLaunchKernelGGL(proj_kernel, pgrid, pblock, 0, stream,
                       X, Wih0, bih0, bhh0, xw);
    {
        const float* xw_c = xw;
        float* hl0 = hlast;
        void* args0[] = {(void*)&xw_c, (void*)&Whh0, (void*)&hq,
                         (void*)&y, (void*)&hl0, (void*)&flags};
        hipLaunchCooperativeKernel((void*)rnn_kernel, rgrid, rblock, args0, 0, stream);
    }

    // ---- layer 1 ----
    hipMemsetAsync(hq, 0, 32768 * sizeof(float4), stream);
    hipMemsetAsync(flags, 0, 256 * sizeof(int), stream);
    hipLaunchKernelGGL(proj_kernel, pgrid, pblock, 0, stream,
                       (const float*)y, Wih1, bih1, bhh1, xw);
    {
        const float* xw_c = xw;
        float* hl1 = hlast + 65536;
        void* args1[] = {(void*)&xw_c, (void*)&Whh1, (void*)&hq,
                         (void*)&y, (void*)&hl1, (void*)&flags};
        hipLaunchCooperativeKernel((void*)rnn_kernel, rgrid, rblock, args1, 0, stream);
    }
}